// Round 4
// baseline (318.551 us; speedup 1.0000x reference)
//
#include <hip/hip_runtime.h>

typedef __bf16 bf16_t;
typedef bf16_t bf16x8 __attribute__((ext_vector_type(8)));
typedef bf16_t bf16x4 __attribute__((ext_vector_type(4)));
typedef bf16_t bf16x2 __attribute__((ext_vector_type(2)));
typedef float f32x4 __attribute__((ext_vector_type(4)));

#define MFMA __builtin_amdgcn_mfma_f32_16x16x32_bf16
#define SWZ(row, off) ((off) ^ (((row) & 7) << 4))

// ws: weights in MFMA A-fragment order: elem((t*8+kk)*512 + lane*8 + j)
//   = W[k = kk*32 + (lane>>4)*8 + j][col = t*16 + (lane&15)]
// Element offsets:
#define F_W1A   0        // 256 cols: 65536
#define F_W2A   65536    // 256 cols: 65536
#define F_W1B   131072   // 512 cols: 131072
#define F_W2B   262144   // 64 cols: 16384
#define F_WB1   278528   // 64 cols: 16384
#define F_WB2A  294912   // 64 cols: 16384
// byte offsets for intermediates
#define OFF_W2OUT  622592ul    // N*64 bf16 = 8 MB
#define OFF_B1ROW  9011200ul   // N*64 bf16 = 8 MB
#define OFF_B2OUT  17399808ul  // N f32

__device__ __forceinline__ bf16x8 cvt8(float4 a, float4 b) {
  bf16x8 v;
  v[0]=(bf16_t)a.x; v[1]=(bf16_t)a.y; v[2]=(bf16_t)a.z; v[3]=(bf16_t)a.w;
  v[4]=(bf16_t)b.x; v[5]=(bf16_t)b.y; v[6]=(bf16_t)b.z; v[7]=(bf16_t)b.w;
  return v;
}

// one thread per 8-elem fragment chunk: 38912 threads total
__global__ __launch_bounds__(256) void cvt_frag(
    const float* __restrict__ W1a, const float* __restrict__ W2a,
    const float* __restrict__ W1b, const float* __restrict__ W2b,
    const float* __restrict__ Wb1, const float* __restrict__ Wb2a,
    bf16_t* __restrict__ ws)
{
  int gid = blockIdx.x * 256 + threadIdx.x;
  const float* src; int start, base, nout;
  if (gid < 8192)       { src = W1a;  start = 0;     base = F_W1A;  nout = 256; }
  else if (gid < 16384) { src = W2a;  start = 8192;  base = F_W2A;  nout = 256; }
  else if (gid < 32768) { src = W1b;  start = 16384; base = F_W1B;  nout = 512; }
  else if (gid < 34816) { src = W2b;  start = 32768; base = F_W2B;  nout = 64;  }
  else if (gid < 36864) { src = Wb1;  start = 34816; base = F_WB1;  nout = 64;  }
  else                  { src = Wb2a; start = 36864; base = F_WB2A; nout = 64;  }
  int local = gid - start;
  int t = local >> 9, kk = (local >> 6) & 7, l = local & 63;
  int n  = t * 16 + (l & 15);
  int k0 = kk * 32 + (l >> 4) * 8;
  bf16x8 v;
  #pragma unroll
  for (int j = 0; j < 8; ++j) v[j] = (bf16_t)src[(k0 + j) * nout + n];
  *(bf16x8*)(ws + base + (size_t)local * 8) = v;
}

// ---- kA: W2a->h2->W2b->w2; Wb1->b1row; Wb2a-chain->b2 ----------------------
// 512 thr (8 waves), 128 rows/block, 4 iters x 32 rows.
__global__ __launch_bounds__(512, 4) void qmix_kA(
    const float* __restrict__ s, const bf16_t* __restrict__ ws,
    const float* __restrict__ b2a, const float* __restrict__ b2b,
    const float* __restrict__ bb1, const float* __restrict__ bb2a,
    const float* __restrict__ Wb2b, const float* __restrict__ bb2b,
    bf16_t* __restrict__ w2out, bf16_t* __restrict__ b1row,
    float* __restrict__ b2out)
{
  __shared__ __align__(16) char sT[2][32 * 512];   // 32 KB
  __shared__ __align__(16) char h2T[32 * 512];     // 16 KB
  __shared__ float b2part[4][32];

  const int tid = threadIdx.x, wave = tid >> 6, lane = tid & 63;
  const int r16 = lane & 15, g = lane >> 4;
  const int row0 = blockIdx.x * 128;
  const int srow = tid >> 4, sc = tid & 15;

  // persistent W2a tiles {wave, wave+8} (frag-order, coalesced)
  bf16x8 aW[2][8];
  #pragma unroll
  for (int t = 0; t < 2; ++t)
    #pragma unroll
    for (int kk = 0; kk < 8; ++kk)
      aW[t][kk] = *(const bf16x8*)(ws + F_W2A + ((size_t)((wave + t * 8) * 8 + kk) << 9) + lane * 8);

  {
    const float* p = s + (size_t)(row0 + srow) * 256 + sc * 16;
    *(bf16x8*)(&sT[0][srow * 512 + SWZ(srow, sc * 32)]) =
        cvt8(((const float4*)p)[0], ((const float4*)p)[1]);
    *(bf16x8*)(&sT[0][srow * 512 + SWZ(srow, sc * 32 + 16)]) =
        cvt8(((const float4*)p)[2], ((const float4*)p)[3]);
  }
  __syncthreads();

  const float bb2b0 = bb2b[0];
  const bf16_t* smBase = (wave < 4) ? (ws + F_WB1 + ((size_t)wave * 8 << 9))
                                    : (ws + F_WB2A + ((size_t)(wave - 4) * 8 << 9));

  for (int rt = 0; rt < 4; ++rt) {
    const int cur = rt & 1;
    const int rowt = row0 + rt * 32;
    bf16x8 pr0, pr1;
    if (rt < 3) {
      const float* p = s + (size_t)(rowt + 32 + srow) * 256 + sc * 16;
      pr0 = cvt8(((const float4*)p)[0], ((const float4*)p)[1]);
      pr1 = cvt8(((const float4*)p)[2], ((const float4*)p)[3]);
    }
    // stage1: h2 (2 tiles) + small (1 tile), K=256
    f32x4 acc[2][2], accS[2];
    acc[0][0]=(f32x4)0.f; acc[0][1]=(f32x4)0.f;
    acc[1][0]=(f32x4)0.f; acc[1][1]=(f32x4)0.f;
    accS[0]=(f32x4)0.f; accS[1]=(f32x4)0.f;
    #pragma unroll
    for (int kk = 0; kk < 8; ++kk) {
      bf16x8 aS = *(const bf16x8*)(smBase + (kk << 9) + lane * 8);
      #pragma unroll
      for (int h = 0; h < 2; ++h) {
        int rr = h * 16 + r16;
        bf16x8 sB = *(const bf16x8*)(&sT[cur][rr * 512 + SWZ(rr, kk * 64 + g * 16)]);
        acc[0][h] = MFMA(aW[0][kk], sB, acc[0][h], 0, 0, 0);
        acc[1][h] = MFMA(aW[1][kk], sB, acc[1][h], 0, 0, 0);
        accS[h]   = MFMA(aS,        sB, accS[h],   0, 0, 0);
      }
    }
    // h2 = relu(+b2a) -> h2T
    #pragma unroll
    for (int t = 0; t < 2; ++t) {
      float4 b0 = *(const float4*)(b2a + (wave + t * 8) * 16 + 4 * g);
      #pragma unroll
      for (int h = 0; h < 2; ++h) {
        int rr = h * 16 + r16;
        bf16x4 hv;
        hv[0]=(bf16_t)fmaxf(acc[t][h][0]+b0.x,0.f); hv[1]=(bf16_t)fmaxf(acc[t][h][1]+b0.y,0.f);
        hv[2]=(bf16_t)fmaxf(acc[t][h][2]+b0.z,0.f); hv[3]=(bf16_t)fmaxf(acc[t][h][3]+b0.w,0.f);
        *(bf16x4*)(&h2T[rr * 512 + SWZ(rr, (wave + t * 8) * 32 + 8 * g)]) = hv;
      }
    }
    // small epilogues
    if (wave < 4) {
      float4 bb = *(const float4*)(bb1 + wave * 16 + 4 * g);
      #pragma unroll
      for (int h = 0; h < 2; ++h) {
        bf16x4 o;
        o[0]=(bf16_t)(accS[h][0]+bb.x); o[1]=(bf16_t)(accS[h][1]+bb.y);
        o[2]=(bf16_t)(accS[h][2]+bb.z); o[3]=(bf16_t)(accS[h][3]+bb.w);
        *(bf16x4*)(b1row + (size_t)(rowt + h * 16 + r16) * 64 + wave * 16 + 4 * g) = o;
      }
    } else {
      float4 ba = *(const float4*)(bb2a + (wave - 4) * 16 + 4 * g);
      float4 wv = *(const float4*)(Wb2b + (wave - 4) * 16 + 4 * g);
      #pragma unroll
      for (int h = 0; h < 2; ++h) {
        float part = fmaxf(accS[h][0]+ba.x,0.f)*wv.x + fmaxf(accS[h][1]+ba.y,0.f)*wv.y
                   + fmaxf(accS[h][2]+ba.z,0.f)*wv.z + fmaxf(accS[h][3]+ba.w,0.f)*wv.w;
        part += __shfl_xor(part, 16); part += __shfl_xor(part, 32);
        if (lane < 16) b2part[wave - 4][h * 16 + r16] = part;
      }
    }
    __syncthreads();  // A: h2T, b2part visible
    if (rt < 3) {
      *(bf16x8*)(&sT[cur ^ 1][srow * 512 + SWZ(srow, sc * 32)])      = pr0;
      *(bf16x8*)(&sT[cur ^ 1][srow * 512 + SWZ(srow, sc * 32 + 16)]) = pr1;
    }
    // stage2: w2 = |h2 @ W2b + b2b|; tile ct = wave>>1, half = wave&1
    {
      const int ct = wave >> 1, h = wave & 1, rr = h * 16 + r16;
      f32x4 accV = (f32x4)0.f;
      #pragma unroll
      for (int kk = 0; kk < 8; ++kk) {
        bf16x8 aV = *(const bf16x8*)(ws + F_W2B + ((size_t)(ct * 8 + kk) << 9) + lane * 8);
        bf16x8 hB = *(const bf16x8*)(&h2T[rr * 512 + SWZ(rr, kk * 64 + g * 16)]);
        accV = MFMA(aV, hB, accV, 0, 0, 0);
      }
      float4 bv = *(const float4*)(b2b + ct * 16 + 4 * g);
      bf16x4 o;
      o[0]=(bf16_t)fabsf(accV[0]+bv.x); o[1]=(bf16_t)fabsf(accV[1]+bv.y);
      o[2]=(bf16_t)fabsf(accV[2]+bv.z); o[3]=(bf16_t)fabsf(accV[3]+bv.w);
      *(bf16x4*)(w2out + (size_t)(rowt + h * 16 + r16) * 64 + ct * 16 + 4 * g) = o;
    }
    if (wave == 7 && lane < 32)
      b2out[rowt + lane] = b2part[0][lane] + b2part[1][lane]
                         + b2part[2][lane] + b2part[3][lane] + bb2b0;
    __syncthreads();  // B
  }
}

// ---- kB: W1a->h1 (LDS only) -> W1b -> q-fold -> elu -> dot w2 -> out -------
__global__ __launch_bounds__(512, 4) void qmix_kB(
    const float* __restrict__ s, const float* __restrict__ q,
    const bf16_t* __restrict__ ws,
    const float* __restrict__ b1a, const float* __restrict__ b1b,
    const bf16_t* __restrict__ w2in, const bf16_t* __restrict__ b1row,
    const float* __restrict__ b2in, float* __restrict__ out)
{
  __shared__ __align__(16) char sT[32 * 512];      // 16 KB (single)
  __shared__ __align__(16) char h1T[32 * 512];     // 16 KB
  __shared__ __align__(16) char slab[8 * 4096];    // 32 KB: 8 agents x 16 rows x 64 f32

  const int tid = threadIdx.x, wave = tid >> 6, lane = tid & 63;
  const int r16 = lane & 15, g = lane >> 4;
  const int row0 = blockIdx.x * 128;
  const int srow = tid >> 4, sc = tid & 15;

  // persistent: W1b tile (wave*4 + 0)
  bf16x8 aP[8];
  #pragma unroll
  for (int kk = 0; kk < 8; ++kk)
    aP[kk] = *(const bf16x8*)(ws + F_W1B + ((size_t)(wave * 4 * 8 + kk) << 9) + lane * 8);

  {
    const float* p = s + (size_t)(row0 + srow) * 256 + sc * 16;
    *(bf16x8*)(&sT[srow * 512 + SWZ(srow, sc * 32)]) =
        cvt8(((const float4*)p)[0], ((const float4*)p)[1]);
    *(bf16x8*)(&sT[srow * 512 + SWZ(srow, sc * 32 + 16)]) =
        cvt8(((const float4*)p)[2], ((const float4*)p)[3]);
  }
  __syncthreads();

  for (int rt = 0; rt < 4; ++rt) {
    const int rowt = row0 + rt * 32;
    bf16x8 pr0, pr1;
    if (rt < 3) {
      const float* p = s + (size_t)(rowt + 32 + srow) * 256 + sc * 16;
      pr0 = cvt8(((const float4*)p)[0], ((const float4*)p)[1]);
      pr1 = cvt8(((const float4*)p)[2], ((const float4*)p)[3]);
    }
    // stage1: h1 = relu(s @ W1a + b1a), tiles {wave, wave+8}
    f32x4 a1[2][2];
    a1[0][0]=(f32x4)0.f; a1[0][1]=(f32x4)0.f; a1[1][0]=(f32x4)0.f; a1[1][1]=(f32x4)0.f;
    #pragma unroll
    for (int kk = 0; kk < 8; ++kk) {
      bf16x8 aA0 = *(const bf16x8*)(ws + F_W1A + ((size_t)(wave * 8 + kk) << 9) + lane * 8);
      bf16x8 aA1 = *(const bf16x8*)(ws + F_W1A + ((size_t)((wave + 8) * 8 + kk) << 9) + lane * 8);
      #pragma unroll
      for (int h = 0; h < 2; ++h) {
        int rr = h * 16 + r16;
        bf16x8 sB = *(const bf16x8*)(&sT[rr * 512 + SWZ(rr, kk * 64 + g * 16)]);
        a1[0][h] = MFMA(aA0, sB, a1[0][h], 0, 0, 0);
        a1[1][h] = MFMA(aA1, sB, a1[1][h], 0, 0, 0);
      }
    }
    #pragma unroll
    for (int t = 0; t < 2; ++t) {
      float4 b0 = *(const float4*)(b1a + (wave + t * 8) * 16 + 4 * g);
      #pragma unroll
      for (int h = 0; h < 2; ++h) {
        int rr = h * 16 + r16;
        bf16x4 hv;
        hv[0]=(bf16_t)fmaxf(a1[t][h][0]+b0.x,0.f); hv[1]=(bf16_t)fmaxf(a1[t][h][1]+b0.y,0.f);
        hv[2]=(bf16_t)fmaxf(a1[t][h][2]+b0.z,0.f); hv[3]=(bf16_t)fmaxf(a1[t][h][3]+b0.w,0.f);
        *(bf16x4*)(&h1T[rr * 512 + SWZ(rr, (wave + t * 8) * 32 + 8 * g)]) = hv;
      }
    }
    __syncthreads();  // A: h1T ready, sT consumed
    if (rt < 3) {
      *(bf16x8*)(&sT[srow * 512 + SWZ(srow, sc * 32)])      = pr0;
      *(bf16x8*)(&sT[srow * 512 + SWZ(srow, sc * 32 + 16)]) = pr1;
    }
    // stage2: w1 tiles (wave*4 + tt), both row halves
    float qa0 = q[(size_t)(rowt + r16) * 8 + wave];
    float qa1 = q[(size_t)(rowt + 16 + r16) * 8 + wave];
    f32x4 a2[4][2];
    #pragma unroll
    for (int tt = 0; tt < 4; ++tt) { a2[tt][0]=(f32x4)0.f; a2[tt][1]=(f32x4)0.f; }
    #pragma unroll
    for (int kk = 0; kk < 8; ++kk) {
      bf16x8 hB0 = *(const bf16x8*)(&h1T[r16 * 512 + SWZ(r16, kk * 64 + g * 16)]);
      int rr1 = 16 + r16;
      bf16x8 hB1 = *(const bf16x8*)(&h1T[rr1 * 512 + SWZ(rr1, kk * 64 + g * 16)]);
      a2[0][0] = MFMA(aP[kk], hB0, a2[0][0], 0, 0, 0);
      a2[0][1] = MFMA(aP[kk], hB1, a2[0][1], 0, 0, 0);
      #pragma unroll
      for (int tt = 1; tt < 4; ++tt) {
        bf16x8 aT = *(const bf16x8*)(ws + F_W1B + ((size_t)((wave * 4 + tt) * 8 + kk) << 9) + lane * 8);
        a2[tt][0] = MFMA(aT, hB0, a2[tt][0], 0, 0, 0);
        a2[tt][1] = MFMA(aT, hB1, a2[tt][1], 0, 0, 0);
      }
    }
    // fold + reduce, 16-row halves
    #pragma unroll
    for (int h = 0; h < 2; ++h) {
      float qa = h ? qa1 : qa0;
      #pragma unroll
      for (int tt = 0; tt < 4; ++tt) {
        float4 bb = *(const float4*)(b1b + wave * 64 + tt * 16 + 4 * g);
        f32x4 v;
        v[0]=qa*fabsf(a2[tt][h][0]+bb.x); v[1]=qa*fabsf(a2[tt][h][1]+bb.y);
        v[2]=qa*fabsf(a2[tt][h][2]+bb.z); v[3]=qa*fabsf(a2[tt][h][3]+bb.w);
        *(f32x4*)(&slab[wave * 4096 + r16 * 256 + SWZ(r16, tt * 64 + g * 16)]) = v;
      }
      __syncthreads();  // slab[h] ready
      {
        int row = tid >> 5, c2 = (tid & 31) * 2;
        float s0 = 0.f, s1 = 0.f;
        #pragma unroll
        for (int a = 0; a < 8; ++a) {
          float2 sv = *(const float2*)(&slab[a * 4096 + row * 256 + SWZ(row, c2 * 4)]);
          s0 += sv.x; s1 += sv.y;
        }
        int grow = rowt + h * 16 + row;
        bf16x2 b1v = *(const bf16x2*)(b1row + (size_t)grow * 64 + c2);
        bf16x2 w2v = *(const bf16x2*)(w2in + (size_t)grow * 64 + c2);
        float h0 = s0 + (float)b1v[0], h1 = s1 + (float)b1v[1];
        h0 = h0 > 0.f ? h0 : (__expf(h0) - 1.f);
        h1 = h1 > 0.f ? h1 : (__expf(h1) - 1.f);
        float dot = h0 * (float)w2v[0] + h1 * (float)w2v[1];
        dot += __shfl_xor(dot, 1); dot += __shfl_xor(dot, 2);
        dot += __shfl_xor(dot, 4); dot += __shfl_xor(dot, 8);
        dot += __shfl_xor(dot, 16);
        if ((tid & 31) == 0) out[grow] = dot + b2in[grow];
      }
      __syncthreads();  // slab consumed
    }
  }
}

extern "C" void kernel_launch(void* const* d_in, const int* in_sizes, int n_in,
                              void* d_out, int out_size, void* d_ws, size_t ws_size,
                              hipStream_t stream) {
  const float* q    = (const float*)d_in[0];
  const float* s    = (const float*)d_in[1];
  const float* W1a  = (const float*)d_in[2];
  const float* b1a  = (const float*)d_in[3];
  const float* W1b  = (const float*)d_in[4];
  const float* b1b  = (const float*)d_in[5];
  const float* W2a  = (const float*)d_in[6];
  const float* b2a  = (const float*)d_in[7];
  const float* W2b  = (const float*)d_in[8];
  const float* b2b  = (const float*)d_in[9];
  const float* Wb1  = (const float*)d_in[10];
  const float* bb1  = (const float*)d_in[11];
  const float* Wb2a = (const float*)d_in[12];
  const float* bb2a = (const float*)d_in[13];
  const float* Wb2b = (const float*)d_in[14];
  const float* bb2b = (const float*)d_in[15];
  bf16_t* ws = (bf16_t*)d_ws;
  float* out = (float*)d_out;

  bf16_t* w2out = (bf16_t*)((char*)d_ws + OFF_W2OUT);
  bf16_t* b1row = (bf16_t*)((char*)d_ws + OFF_B1ROW);
  float*  b2out = (float*)((char*)d_ws + OFF_B2OUT);

  int N  = in_sizes[0] / 8;       // 65536 rows
  int nb = N / 128;               // 512 blocks

  cvt_frag<<<152, 256, 0, stream>>>(W1a, W2a, W1b, W2b, Wb1, Wb2a, ws);
  qmix_kA<<<nb, 512, 0, stream>>>(s, ws, b2a, b2b, bb1, bb2a, Wb2b, bb2b,
                                  w2out, b1row, b2out);
  qmix_kB<<<nb, 512, 0, stream>>>(s, q, ws, b1a, b1b, w2out, b1row, b2out, out);
}

// Round 5
// 212.536 us; speedup vs baseline: 1.4988x; 1.4988x over previous
//
#include <hip/hip_runtime.h>

typedef __bf16 bf16_t;
typedef bf16_t bf16x8 __attribute__((ext_vector_type(8)));
typedef bf16_t bf16x4 __attribute__((ext_vector_type(4)));
typedef float f32x4 __attribute__((ext_vector_type(4)));

#define MFMA __builtin_amdgcn_mfma_f32_16x16x32_bf16
#define SWZ(row, off) ((off) ^ (((row) & 7) << 4))

// ws: weights in MFMA A-fragment order: elem((t*8+kk)*512 + lane*8 + j)
//   = W[k = kk*32 + (lane>>4)*8 + j][col = t*16 + (lane&15)]
#define F_W1A   0        // 256 cols: 65536 elems
#define F_W2A   65536    // 256 cols: 65536
#define F_W1B   131072   // 512 cols: 131072
#define F_W2B   262144   // 64 cols: 16384
#define F_WB1   278528   // 64 cols: 16384
#define F_WB2A  294912   // 64 cols: 16384

__device__ __forceinline__ bf16x8 cvt8(float4 a, float4 b) {
  bf16x8 v;
  v[0]=(bf16_t)a.x; v[1]=(bf16_t)a.y; v[2]=(bf16_t)a.z; v[3]=(bf16_t)a.w;
  v[4]=(bf16_t)b.x; v[5]=(bf16_t)b.y; v[6]=(bf16_t)b.z; v[7]=(bf16_t)b.w;
  return v;
}

// one thread per 8-elem fragment chunk: 38912 threads (verified correct in R4)
__global__ __launch_bounds__(256) void cvt_frag(
    const float* __restrict__ W1a, const float* __restrict__ W2a,
    const float* __restrict__ W1b, const float* __restrict__ W2b,
    const float* __restrict__ Wb1, const float* __restrict__ Wb2a,
    bf16_t* __restrict__ ws)
{
  int gid = blockIdx.x * 256 + threadIdx.x;
  const float* src; int start, base, nout;
  if (gid < 8192)       { src = W1a;  start = 0;     base = F_W1A;  nout = 256; }
  else if (gid < 16384) { src = W2a;  start = 8192;  base = F_W2A;  nout = 256; }
  else if (gid < 32768) { src = W1b;  start = 16384; base = F_W1B;  nout = 512; }
  else if (gid < 34816) { src = W2b;  start = 32768; base = F_W2B;  nout = 64;  }
  else if (gid < 36864) { src = Wb1;  start = 34816; base = F_WB1;  nout = 64;  }
  else                  { src = Wb2a; start = 36864; base = F_WB2A; nout = 64;  }
  int local = gid - start;
  int t = local >> 9, kk = (local >> 6) & 7, l = local & 63;
  int n  = t * 16 + (l & 15);
  int k0 = kk * 32 + (l >> 4) * 8;
  bf16x8 v;
  #pragma unroll
  for (int j = 0; j < 8; ++j) v[j] = (bf16_t)src[(k0 + j) * nout + n];
  *(bf16x8*)(ws + base + (size_t)local * 8) = v;
}

// ---- single fused kernel: 512 thr (8 waves), 256 rows/block, 8 x 32-row tiles
__global__ __launch_bounds__(512, 2) void qmix_fused(
    const float* __restrict__ s, const float* __restrict__ q,
    const bf16_t* __restrict__ ws,
    const float* __restrict__ b1a, const float* __restrict__ b2a,
    const float* __restrict__ b1b, const float* __restrict__ b2b,
    const float* __restrict__ bb1, const float* __restrict__ bb2a,
    const float* __restrict__ Wb2b, const float* __restrict__ bb2b,
    float* __restrict__ out)
{
  __shared__ __align__(16) char sT[2][16384];   // s tiles, 32 rows x 512B bf16
  __shared__ __align__(16) char h1T[16384];
  __shared__ __align__(16) char h2T[16384];
  __shared__ __align__(16) char slab[65536];    // 8 agents x 32 rows x 64 f32
  __shared__ __align__(16) char b1T[4096];      // 32 rows x 64 bf16
  __shared__ __align__(16) char w2T[4096];      // 32 rows x 64 bf16
  __shared__ float b2part[4][32];

  const int tid = threadIdx.x, wave = tid >> 6, lane = tid & 63;
  const int r16 = lane & 15, g = lane >> 4;
  const int row0 = blockIdx.x * 256;
  const int srow = tid >> 4, sc = tid & 15;

  // ---- persistent fragments: 128 VGPR
  bf16x8 aA[2][8], aSm[8], aB0[8];
  #pragma unroll
  for (int t = 0; t < 2; ++t)
    #pragma unroll
    for (int kk = 0; kk < 8; ++kk)
      aA[t][kk] = *(const bf16x8*)(ws + F_W1A + ((size_t)((wave + t * 8) * 8 + kk) << 9) + lane * 8);
  {
    const bf16_t* smB = ws + ((wave < 4) ? (F_WB1 + ((size_t)(wave * 8) << 9))
                                         : (F_WB2A + ((size_t)((wave - 4) * 8) << 9)));
    #pragma unroll
    for (int kk = 0; kk < 8; ++kk)
      aSm[kk] = *(const bf16x8*)(smB + ((size_t)kk << 9) + lane * 8);
  }
  #pragma unroll
  for (int kk = 0; kk < 8; ++kk)
    aB0[kk] = *(const bf16x8*)(ws + F_W1B + ((size_t)(wave * 4 * 8 + kk) << 9) + lane * 8);

  // ---- initial s tile
  {
    const float* p = s + (size_t)(row0 + srow) * 256 + sc * 16;
    *(bf16x8*)(&sT[0][srow * 512 + SWZ(srow, sc * 32)]) =
        cvt8(((const float4*)p)[0], ((const float4*)p)[1]);
    *(bf16x8*)(&sT[0][srow * 512 + SWZ(srow, sc * 32 + 16)]) =
        cvt8(((const float4*)p)[2], ((const float4*)p)[3]);
  }
  __syncthreads();

  const float bb2b0 = bb2b[0];

  #pragma unroll 1
  for (int rt = 0; rt < 8; ++rt) {
    const int cur = rt & 1;
    const int rowt = row0 + rt * 32;
    bf16x8 pr0, pr1;
    if (rt < 7) {
      const float* p = s + (size_t)(rowt + 32 + srow) * 256 + sc * 16;
      pr0 = cvt8(((const float4*)p)[0], ((const float4*)p)[1]);
      pr1 = cvt8(((const float4*)p)[2], ((const float4*)p)[3]);
    }
    // ======== phase 1: h1 (W1a persist x2), h2 (W2a streamed x2), small x1
    f32x4 a1[2][2], ah[2][2], aS[2];
    a1[0][0]=(f32x4)0.f; a1[0][1]=(f32x4)0.f; a1[1][0]=(f32x4)0.f; a1[1][1]=(f32x4)0.f;
    ah[0][0]=(f32x4)0.f; ah[0][1]=(f32x4)0.f; ah[1][0]=(f32x4)0.f; ah[1][1]=(f32x4)0.f;
    aS[0]=(f32x4)0.f; aS[1]=(f32x4)0.f;
    const bf16_t* w2aP0 = ws + F_W2A + ((size_t)(wave * 8) << 9) + lane * 8;
    const bf16_t* w2aP1 = ws + F_W2A + ((size_t)((wave + 8) * 8) << 9) + lane * 8;
    bf16x8 c0n = *(const bf16x8*)(w2aP0);
    bf16x8 c1n = *(const bf16x8*)(w2aP1);
    #pragma unroll
    for (int kk = 0; kk < 8; ++kk) {
      bf16x8 c0 = c0n, c1 = c1n;
      if (kk < 7) {
        c0n = *(const bf16x8*)(w2aP0 + (kk + 1) * 512);
        c1n = *(const bf16x8*)(w2aP1 + (kk + 1) * 512);
      }
      #pragma unroll
      for (int h = 0; h < 2; ++h) {
        int rr = h * 16 + r16;
        bf16x8 sB = *(const bf16x8*)(&sT[cur][rr * 512 + SWZ(rr, kk * 64 + g * 16)]);
        a1[0][h] = MFMA(aA[0][kk], sB, a1[0][h], 0, 0, 0);
        a1[1][h] = MFMA(aA[1][kk], sB, a1[1][h], 0, 0, 0);
        ah[0][h] = MFMA(c0, sB, ah[0][h], 0, 0, 0);
        ah[1][h] = MFMA(c1, sB, ah[1][h], 0, 0, 0);
        aS[h]    = MFMA(aSm[kk], sB, aS[h], 0, 0, 0);
      }
    }
    // epilogue 1: h1->h1T, h2->h2T, smalls
    #pragma unroll
    for (int t = 0; t < 2; ++t) {
      float4 bh1 = *(const float4*)(b1a + (wave + t * 8) * 16 + 4 * g);
      float4 bh2 = *(const float4*)(b2a + (wave + t * 8) * 16 + 4 * g);
      #pragma unroll
      for (int h = 0; h < 2; ++h) {
        int rr = h * 16 + r16;
        bf16x4 v1, v2;
        v1[0]=(bf16_t)fmaxf(a1[t][h][0]+bh1.x,0.f); v1[1]=(bf16_t)fmaxf(a1[t][h][1]+bh1.y,0.f);
        v1[2]=(bf16_t)fmaxf(a1[t][h][2]+bh1.z,0.f); v1[3]=(bf16_t)fmaxf(a1[t][h][3]+bh1.w,0.f);
        v2[0]=(bf16_t)fmaxf(ah[t][h][0]+bh2.x,0.f); v2[1]=(bf16_t)fmaxf(ah[t][h][1]+bh2.y,0.f);
        v2[2]=(bf16_t)fmaxf(ah[t][h][2]+bh2.z,0.f); v2[3]=(bf16_t)fmaxf(ah[t][h][3]+bh2.w,0.f);
        *(bf16x4*)(&h1T[rr * 512 + SWZ(rr, (wave + t * 8) * 32 + 8 * g)]) = v1;
        *(bf16x4*)(&h2T[rr * 512 + SWZ(rr, (wave + t * 8) * 32 + 8 * g)]) = v2;
      }
    }
    if (wave < 4) {
      float4 bb = *(const float4*)(bb1 + wave * 16 + 4 * g);
      #pragma unroll
      for (int h = 0; h < 2; ++h) {
        int rr = h * 16 + r16;
        bf16x4 o;
        o[0]=(bf16_t)(aS[h][0]+bb.x); o[1]=(bf16_t)(aS[h][1]+bb.y);
        o[2]=(bf16_t)(aS[h][2]+bb.z); o[3]=(bf16_t)(aS[h][3]+bb.w);
        *(bf16x4*)(&b1T[rr * 128 + wave * 32 + 8 * g]) = o;
      }
    } else {
      float4 ba = *(const float4*)(bb2a + (wave - 4) * 16 + 4 * g);
      float4 wv = *(const float4*)(Wb2b + (wave - 4) * 16 + 4 * g);
      #pragma unroll
      for (int h = 0; h < 2; ++h) {
        float part = fmaxf(aS[h][0]+ba.x,0.f)*wv.x + fmaxf(aS[h][1]+ba.y,0.f)*wv.y
                   + fmaxf(aS[h][2]+ba.z,0.f)*wv.z + fmaxf(aS[h][3]+ba.w,0.f)*wv.w;
        part += __shfl_xor(part, 16); part += __shfl_xor(part, 32);
        if (lane < 16) b2part[wave - 4][h * 16 + r16] = part;
      }
    }
    __syncthreads();  // A: h1T/h2T/b1T/b2part visible
    if (rt < 7) {
      *(bf16x8*)(&sT[cur ^ 1][srow * 512 + SWZ(srow, sc * 32)])      = pr0;
      *(bf16x8*)(&sT[cur ^ 1][srow * 512 + SWZ(srow, sc * 32 + 16)]) = pr1;
    }
    // ======== phase 2: w1 = |h1@W1b+b1b| (1 persist + 3 streamed tiles),
    //                   w2 = |h2@W2b+b2b| (waves 0-3)
    float qa0 = q[(size_t)(rowt + r16) * 8 + wave];
    float qa1 = q[(size_t)(rowt + 16 + r16) * 8 + wave];
    f32x4 w1acc[4][2];
    #pragma unroll
    for (int tt = 0; tt < 4; ++tt) { w1acc[tt][0]=(f32x4)0.f; w1acc[tt][1]=(f32x4)0.f; }
    f32x4 vacc0 = (f32x4)0.f, vacc1 = (f32x4)0.f;
    const bf16_t* w1bP1 = ws + F_W1B + ((size_t)((wave * 4 + 1) * 8) << 9) + lane * 8;
    const bf16_t* w1bP2 = ws + F_W1B + ((size_t)((wave * 4 + 2) * 8) << 9) + lane * 8;
    const bf16_t* w1bP3 = ws + F_W1B + ((size_t)((wave * 4 + 3) * 8) << 9) + lane * 8;
    const bf16_t* w2bP  = ws + F_W2B + ((size_t)((wave & 3) * 8) << 9) + lane * 8;
    bf16x8 t1n = *(const bf16x8*)(w1bP1);
    bf16x8 t2n = *(const bf16x8*)(w1bP2);
    bf16x8 t3n = *(const bf16x8*)(w1bP3);
    bf16x8 tvn = *(const bf16x8*)(w2bP);
    #pragma unroll
    for (int kk = 0; kk < 8; ++kk) {
      bf16x8 t1 = t1n, t2 = t2n, t3 = t3n, tv = tvn;
      if (kk < 7) {
        t1n = *(const bf16x8*)(w1bP1 + (kk + 1) * 512);
        t2n = *(const bf16x8*)(w1bP2 + (kk + 1) * 512);
        t3n = *(const bf16x8*)(w1bP3 + (kk + 1) * 512);
        tvn = *(const bf16x8*)(w2bP  + (kk + 1) * 512);
      }
      bf16x8 hB0 = *(const bf16x8*)(&h1T[r16 * 512 + SWZ(r16, kk * 64 + g * 16)]);
      int rr1 = 16 + r16;
      bf16x8 hB1 = *(const bf16x8*)(&h1T[rr1 * 512 + SWZ(rr1, kk * 64 + g * 16)]);
      w1acc[0][0] = MFMA(aB0[kk], hB0, w1acc[0][0], 0, 0, 0);
      w1acc[0][1] = MFMA(aB0[kk], hB1, w1acc[0][1], 0, 0, 0);
      w1acc[1][0] = MFMA(t1, hB0, w1acc[1][0], 0, 0, 0);
      w1acc[1][1] = MFMA(t1, hB1, w1acc[1][1], 0, 0, 0);
      w1acc[2][0] = MFMA(t2, hB0, w1acc[2][0], 0, 0, 0);
      w1acc[2][1] = MFMA(t2, hB1, w1acc[2][1], 0, 0, 0);
      w1acc[3][0] = MFMA(t3, hB0, w1acc[3][0], 0, 0, 0);
      w1acc[3][1] = MFMA(t3, hB1, w1acc[3][1], 0, 0, 0);
      if (wave < 4) {
        bf16x8 hV0 = *(const bf16x8*)(&h2T[r16 * 512 + SWZ(r16, kk * 64 + g * 16)]);
        bf16x8 hV1 = *(const bf16x8*)(&h2T[rr1 * 512 + SWZ(rr1, kk * 64 + g * 16)]);
        vacc0 = MFMA(tv, hV0, vacc0, 0, 0, 0);
        vacc1 = MFMA(tv, hV1, vacc1, 0, 0, 0);
      }
    }
    // epilogue 2: slab fold + w2T
    #pragma unroll
    for (int tt = 0; tt < 4; ++tt) {
      float4 bb = *(const float4*)(b1b + wave * 64 + tt * 16 + 4 * g);
      #pragma unroll
      for (int h = 0; h < 2; ++h) {
        float qa = h ? qa1 : qa0;
        int rr = h * 16 + r16;
        f32x4 v;
        v[0] = qa * fabsf(w1acc[tt][h][0] + bb.x);
        v[1] = qa * fabsf(w1acc[tt][h][1] + bb.y);
        v[2] = qa * fabsf(w1acc[tt][h][2] + bb.z);
        v[3] = qa * fabsf(w1acc[tt][h][3] + bb.w);
        *(f32x4*)(&slab[wave * 8192 + rr * 256 + SWZ(rr, tt * 64 + g * 16)]) = v;
      }
    }
    if (wave < 4) {
      float4 bv = *(const float4*)(b2b + wave * 16 + 4 * g);
      bf16x4 o0, o1;
      o0[0]=(bf16_t)fabsf(vacc0[0]+bv.x); o0[1]=(bf16_t)fabsf(vacc0[1]+bv.y);
      o0[2]=(bf16_t)fabsf(vacc0[2]+bv.z); o0[3]=(bf16_t)fabsf(vacc0[3]+bv.w);
      o1[0]=(bf16_t)fabsf(vacc1[0]+bv.x); o1[1]=(bf16_t)fabsf(vacc1[1]+bv.y);
      o1[2]=(bf16_t)fabsf(vacc1[2]+bv.z); o1[3]=(bf16_t)fabsf(vacc1[3]+bv.w);
      *(bf16x4*)(&w2T[r16 * 128 + wave * 32 + 8 * g]) = o0;
      *(bf16x4*)(&w2T[(16 + r16) * 128 + wave * 32 + 8 * g]) = o1;
    }
    __syncthreads();  // B: slab/w2T visible
    // fold: hidden = elu(sum_a slab + b1) ; out = hidden . w2 + b2
    {
      const int row = tid >> 4, c = tid & 15;
      f32x4 sum = (f32x4)0.f;
      #pragma unroll
      for (int a = 0; a < 8; ++a)
        sum += *(const f32x4*)(&slab[a * 8192 + row * 256 + SWZ(row, c * 16)]);
      bf16x4 b1v = *(const bf16x4*)(&b1T[row * 128 + c * 8]);
      bf16x4 w2v = *(const bf16x4*)(&w2T[row * 128 + c * 8]);
      float dot = 0.f;
      #pragma unroll
      for (int e = 0; e < 4; ++e) {
        float hh = sum[e] + (float)b1v[e];
        hh = hh > 0.f ? hh : (__expf(hh) - 1.f);
        dot += hh * (float)w2v[e];
      }
      dot += __shfl_xor(dot, 1); dot += __shfl_xor(dot, 2);
      dot += __shfl_xor(dot, 4); dot += __shfl_xor(dot, 8);
      if (c == 0) {
        float b2v = b2part[0][row] + b2part[1][row] + b2part[2][row]
                  + b2part[3][row] + bb2b0;
        out[rowt + row] = dot + b2v;
      }
    }
    __syncthreads();  // C: slab/h-buffers reusable
  }
}

extern "C" void kernel_launch(void* const* d_in, const int* in_sizes, int n_in,
                              void* d_out, int out_size, void* d_ws, size_t ws_size,
                              hipStream_t stream) {
  const float* q    = (const float*)d_in[0];
  const float* s    = (const float*)d_in[1];
  const float* W1a  = (const float*)d_in[2];
  const float* b1a  = (const float*)d_in[3];
  const float* W1b  = (const float*)d_in[4];
  const float* b1b  = (const float*)d_in[5];
  const float* W2a  = (const float*)d_in[6];
  const float* b2a  = (const float*)d_in[7];
  const float* W2b  = (const float*)d_in[8];
  const float* b2b  = (const float*)d_in[9];
  const float* Wb1  = (const float*)d_in[10];
  const float* bb1  = (const float*)d_in[11];
  const float* Wb2a = (const float*)d_in[12];
  const float* bb2a = (const float*)d_in[13];
  const float* Wb2b = (const float*)d_in[14];
  const float* bb2b = (const float*)d_in[15];
  bf16_t* ws = (bf16_t*)d_ws;
  float* out = (float*)d_out;

  int N  = in_sizes[0] / 8;       // 65536 rows
  int nb = N / 256;               // 256 blocks

  cvt_frag<<<152, 256, 0, stream>>>(W1a, W2a, W1b, W2b, Wb1, Wb2a, ws);
  qmix_fused<<<nb, 512, 0, stream>>>(s, q, ws, b1a, b2a, b1b, b2b,
                                     bb1, bb2a, Wb2b, bb2b, out);
}

// Round 6
// 160.506 us; speedup vs baseline: 1.9847x; 1.3242x over previous
//
#include <hip/hip_runtime.h>

typedef __bf16 bf16_t;
typedef bf16_t bf16x8 __attribute__((ext_vector_type(8)));
typedef bf16_t bf16x4 __attribute__((ext_vector_type(4)));
typedef float f32x4 __attribute__((ext_vector_type(4)));

#define MFMA __builtin_amdgcn_mfma_f32_16x16x32_bf16
#define SWZ(row, off) ((off) ^ (((row) & 7) << 4))

// ws: weights in MFMA A-fragment order: elem((t*8+kk)*512 + lane*8 + j)
//   = W[k = kk*32 + (lane>>4)*8 + j][col = t*16 + (lane&15)]
#define F_W1A   0        // 256 cols
#define F_W2A   65536    // 256 cols
#define F_W1B   131072   // 512 cols (tile idx = agent*4 + qhtile)
#define F_W2B   262144   // 64 cols
#define F_WB1   278528   // 64 cols
#define F_WB2A  294912   // 64 cols

__device__ __forceinline__ bf16x8 cvt8(float4 a, float4 b) {
  bf16x8 v;
  v[0]=(bf16_t)a.x; v[1]=(bf16_t)a.y; v[2]=(bf16_t)a.z; v[3]=(bf16_t)a.w;
  v[4]=(bf16_t)b.x; v[5]=(bf16_t)b.y; v[6]=(bf16_t)b.z; v[7]=(bf16_t)b.w;
  return v;
}

__global__ __launch_bounds__(256) void cvt_frag(
    const float* __restrict__ W1a, const float* __restrict__ W2a,
    const float* __restrict__ W1b, const float* __restrict__ W2b,
    const float* __restrict__ Wb1, const float* __restrict__ Wb2a,
    bf16_t* __restrict__ ws)
{
  int gid = blockIdx.x * 256 + threadIdx.x;
  const float* src; int start, base, nout;
  if (gid < 8192)       { src = W1a;  start = 0;     base = F_W1A;  nout = 256; }
  else if (gid < 16384) { src = W2a;  start = 8192;  base = F_W2A;  nout = 256; }
  else if (gid < 32768) { src = W1b;  start = 16384; base = F_W1B;  nout = 512; }
  else if (gid < 34816) { src = W2b;  start = 32768; base = F_W2B;  nout = 64;  }
  else if (gid < 36864) { src = Wb1;  start = 34816; base = F_WB1;  nout = 64;  }
  else                  { src = Wb2a; start = 36864; base = F_WB2A; nout = 64;  }
  int local = gid - start;
  int t = local >> 9, kk = (local >> 6) & 7, l = local & 63;
  int n  = t * 16 + (l & 15);
  int k0 = kk * 32 + (l >> 4) * 8;
  bf16x8 v;
  #pragma unroll
  for (int j = 0; j < 8; ++j) v[j] = (bf16_t)src[(k0 + j) * nout + n];
  *(bf16x8*)(ws + base + (size_t)local * 8) = v;
}

#define FRAG(base, tile, kk) \
  (*(const bf16x8*)(ws + (base) + ((size_t)(((tile) * 8 + (kk))) << 9) + lane * 8))

// single fused kernel: 512 thr (8 waves), 256 rows/block, 4 x 64-row tiles.
// All weights streamed from L2 (frag-order, coalesced). No persistent frags.
__global__ __launch_bounds__(512, 2) void qmix_f2(
    const float* __restrict__ s, const float* __restrict__ q,
    const bf16_t* __restrict__ ws,
    const float* __restrict__ b1a, const float* __restrict__ b2a,
    const float* __restrict__ b1b, const float* __restrict__ b2b,
    const float* __restrict__ bb1, const float* __restrict__ bb2a,
    const float* __restrict__ Wb2b, const float* __restrict__ bb2b,
    float* __restrict__ out)
{
  __shared__ __align__(16) char sT[64 * 512];      // 32K, s tile bf16 swizzled
  __shared__ __align__(16) char h1T[64 * 512];     // 32K
  __shared__ __align__(16) char h2T[64 * 512];     // 32K
  __shared__ __align__(16) char b1T[64 * 128];     // 8K  [row][qh] bf16
  __shared__ __align__(16) char w2T[64 * 128];     // 8K  [row][qh] bf16
  __shared__ __align__(16) char hidT[2][64 * 128]; // 16K [agent-half][row][qh]
  __shared__ float b2part[4][64];                  // 1K

  const int tid = threadIdx.x, wave = tid >> 6, lane = tid & 63;
  const int r16 = lane & 15, g = lane >> 4;
  const int row0 = blockIdx.x * 256;
  const int srow = tid >> 3, sc = tid & 7;   // staging: 64 rows x 8 chunks(32k)

  // prologue: stage tile 0
  {
    const float* p = s + (size_t)(row0 + srow) * 256 + sc * 32;
    #pragma unroll
    for (int j = 0; j < 4; ++j) {
      bf16x8 c = cvt8(((const float4*)p)[j * 2], ((const float4*)p)[j * 2 + 1]);
      *(bf16x8*)(&sT[srow * 512 + SWZ(srow, sc * 64 + j * 16)]) = c;
    }
  }
  __syncthreads();

  const float bb2b0 = bb2b[0];
  const int smBase = (wave < 4) ? (F_WB1 + wave * 4096) : (F_WB2A + (wave - 4) * 4096);

  #pragma unroll 1
  for (int rt = 0; rt < 4; ++rt) {
    const int rowt = row0 + rt * 64;
    // prefetch next s tile into regs (overlaps p1 MFMAs)
    bf16x8 pf[4];
    if (rt < 3) {
      const float* p = s + (size_t)(rowt + 64 + srow) * 256 + sc * 32;
      #pragma unroll
      for (int j = 0; j < 4; ++j)
        pf[j] = cvt8(((const float4*)p)[j * 2], ((const float4*)p)[j * 2 + 1]);
    }
    // ======== phase 1: per wave 5 col-tiles (W1A{w,w+8}, W2A{w,w+8}, small)
    f32x4 acc[5][4];
    #pragma unroll
    for (int t = 0; t < 5; ++t)
      #pragma unroll
      for (int h = 0; h < 4; ++h) acc[t][h] = (f32x4)0.f;
    #pragma unroll
    for (int kk = 0; kk < 8; ++kk) {
      bf16x8 A0 = FRAG(F_W1A, wave, kk);
      bf16x8 A1 = FRAG(F_W1A, wave + 8, kk);
      bf16x8 A2 = FRAG(F_W2A, wave, kk);
      bf16x8 A3 = FRAG(F_W2A, wave + 8, kk);
      bf16x8 A4 = *(const bf16x8*)(ws + smBase + ((size_t)kk << 9) + lane * 8);
      #pragma unroll
      for (int h = 0; h < 4; ++h) {
        int rr = h * 16 + r16;
        bf16x8 B = *(const bf16x8*)(&sT[rr * 512 + SWZ(rr, kk * 64 + g * 16)]);
        acc[0][h] = MFMA(A0, B, acc[0][h], 0, 0, 0);
        acc[1][h] = MFMA(A1, B, acc[1][h], 0, 0, 0);
        acc[2][h] = MFMA(A2, B, acc[2][h], 0, 0, 0);
        acc[3][h] = MFMA(A3, B, acc[3][h], 0, 0, 0);
        acc[4][h] = MFMA(A4, B, acc[4][h], 0, 0, 0);
      }
    }
    // epilogue 1
    #pragma unroll
    for (int t8 = 0; t8 < 2; ++t8) {
      float4 bh1 = *(const float4*)(b1a + (wave + t8 * 8) * 16 + 4 * g);
      float4 bh2 = *(const float4*)(b2a + (wave + t8 * 8) * 16 + 4 * g);
      #pragma unroll
      for (int h = 0; h < 4; ++h) {
        int rr = h * 16 + r16;
        f32x4 x1 = acc[t8][h], x2 = acc[2 + t8][h];
        bf16x4 v1, v2;
        v1[0]=(bf16_t)fmaxf(x1[0]+bh1.x,0.f); v1[1]=(bf16_t)fmaxf(x1[1]+bh1.y,0.f);
        v1[2]=(bf16_t)fmaxf(x1[2]+bh1.z,0.f); v1[3]=(bf16_t)fmaxf(x1[3]+bh1.w,0.f);
        v2[0]=(bf16_t)fmaxf(x2[0]+bh2.x,0.f); v2[1]=(bf16_t)fmaxf(x2[1]+bh2.y,0.f);
        v2[2]=(bf16_t)fmaxf(x2[2]+bh2.z,0.f); v2[3]=(bf16_t)fmaxf(x2[3]+bh2.w,0.f);
        *(bf16x4*)(&h1T[rr * 512 + SWZ(rr, (wave + t8 * 8) * 32 + 8 * g)]) = v1;
        *(bf16x4*)(&h2T[rr * 512 + SWZ(rr, (wave + t8 * 8) * 32 + 8 * g)]) = v2;
      }
    }
    if (wave < 4) {
      float4 bb = *(const float4*)(bb1 + wave * 16 + 4 * g);
      #pragma unroll
      for (int h = 0; h < 4; ++h) {
        int rr = h * 16 + r16;
        bf16x4 o;
        o[0]=(bf16_t)(acc[4][h][0]+bb.x); o[1]=(bf16_t)(acc[4][h][1]+bb.y);
        o[2]=(bf16_t)(acc[4][h][2]+bb.z); o[3]=(bf16_t)(acc[4][h][3]+bb.w);
        *(bf16x4*)(&b1T[rr * 128 + wave * 32 + 8 * g]) = o;
      }
    } else {
      float4 ba = *(const float4*)(bb2a + (wave - 4) * 16 + 4 * g);
      float4 wv = *(const float4*)(Wb2b + (wave - 4) * 16 + 4 * g);
      #pragma unroll
      for (int h = 0; h < 4; ++h) {
        f32x4 x = acc[4][h];
        float part = fmaxf(x[0]+ba.x,0.f)*wv.x + fmaxf(x[1]+ba.y,0.f)*wv.y
                   + fmaxf(x[2]+ba.z,0.f)*wv.z + fmaxf(x[3]+ba.w,0.f)*wv.w;
        part += __shfl_xor(part, 16); part += __shfl_xor(part, 32);
        if (lane < 16) b2part[wave - 4][h * 16 + r16] = part;
      }
    }
    __syncthreads();  // A: h1T/h2T/b1T/b2part ready; sT free
    // stage next s tile (p2 does not read sT)
    if (rt < 3) {
      #pragma unroll
      for (int j = 0; j < 4; ++j)
        *(bf16x8*)(&sT[srow * 512 + SWZ(srow, sc * 64 + j * 16)]) = pf[j];
    }
    // ======== phase 2a: w2 = |h2 @ W2b + b2b|  (wave -> tile w&3, halves w>>2)
    {
      const int t2 = wave & 3, hs = wave >> 2;
      f32x4 av[2]; av[0] = (f32x4)0.f; av[1] = (f32x4)0.f;
      #pragma unroll
      for (int kk = 0; kk < 8; ++kk) {
        bf16x8 A = FRAG(F_W2B, t2, kk);
        #pragma unroll
        for (int hh = 0; hh < 2; ++hh) {
          int rr = (hs * 2 + hh) * 16 + r16;
          bf16x8 B = *(const bf16x8*)(&h2T[rr * 512 + SWZ(rr, kk * 64 + g * 16)]);
          av[hh] = MFMA(A, B, av[hh], 0, 0, 0);
        }
      }
      float4 bv = *(const float4*)(b2b + t2 * 16 + 4 * g);
      #pragma unroll
      for (int hh = 0; hh < 2; ++hh) {
        int rr = (hs * 2 + hh) * 16 + r16;
        bf16x4 o;
        o[0]=(bf16_t)fabsf(av[hh][0]+bv.x); o[1]=(bf16_t)fabsf(av[hh][1]+bv.y);
        o[2]=(bf16_t)fabsf(av[hh][2]+bv.z); o[3]=(bf16_t)fabsf(av[hh][3]+bv.w);
        *(bf16x4*)(&w2T[rr * 128 + t2 * 32 + 8 * g]) = o;
      }
    }
    // ======== phase 2b: w1 fold (wave -> qh-tile t=w&3, agent-half as=w>>2)
    {
      const int t = wave & 3, as = wave >> 2;
      f32x4 hid[4];
      #pragma unroll
      for (int h = 0; h < 4; ++h) hid[h] = (f32x4)0.f;
      #pragma unroll
      for (int ap = 0; ap < 2; ++ap) {
        const int a0 = as * 4 + 2 * ap;
        f32x4 a2[2][4];
        #pragma unroll
        for (int j = 0; j < 2; ++j)
          #pragma unroll
          for (int h = 0; h < 4; ++h) a2[j][h] = (f32x4)0.f;
        #pragma unroll
        for (int kk = 0; kk < 8; ++kk) {
          bf16x8 A0 = FRAG(F_W1B, a0 * 4 + t, kk);
          bf16x8 A1 = FRAG(F_W1B, (a0 + 1) * 4 + t, kk);
          #pragma unroll
          for (int h = 0; h < 4; ++h) {
            int rr = h * 16 + r16;
            bf16x8 B = *(const bf16x8*)(&h1T[rr * 512 + SWZ(rr, kk * 64 + g * 16)]);
            a2[0][h] = MFMA(A0, B, a2[0][h], 0, 0, 0);
            a2[1][h] = MFMA(A1, B, a2[1][h], 0, 0, 0);
          }
        }
        #pragma unroll
        for (int j = 0; j < 2; ++j) {
          const int a = a0 + j;
          float4 bb = *(const float4*)(b1b + a * 64 + t * 16 + 4 * g);
          #pragma unroll
          for (int h = 0; h < 4; ++h) {
            float qa = q[(size_t)(rowt + h * 16 + r16) * 8 + a];
            hid[h][0] += qa * fabsf(a2[j][h][0] + bb.x);
            hid[h][1] += qa * fabsf(a2[j][h][1] + bb.y);
            hid[h][2] += qa * fabsf(a2[j][h][2] + bb.z);
            hid[h][3] += qa * fabsf(a2[j][h][3] + bb.w);
          }
        }
      }
      #pragma unroll
      for (int h = 0; h < 4; ++h) {
        int rr = h * 16 + r16;
        bf16x4 o;
        o[0]=(bf16_t)hid[h][0]; o[1]=(bf16_t)hid[h][1];
        o[2]=(bf16_t)hid[h][2]; o[3]=(bf16_t)hid[h][3];
        *(bf16x4*)(&hidT[as][rr * 128 + t * 32 + 8 * g]) = o;
      }
    }
    __syncthreads();  // B: hidT/w2T ready
    // ======== final fold: hidden = elu(hid0+hid1+b1); out = hidden.w2 + b2
    {
      const int row = tid >> 3, c8 = (tid & 7) * 16;  // 8 threads/row, 8 qh each
      bf16x8 hA = *(const bf16x8*)(&hidT[0][row * 128 + c8]);
      bf16x8 hB = *(const bf16x8*)(&hidT[1][row * 128 + c8]);
      bf16x8 bv = *(const bf16x8*)(&b1T[row * 128 + c8]);
      bf16x8 wv = *(const bf16x8*)(&w2T[row * 128 + c8]);
      float d = 0.f;
      #pragma unroll
      for (int e = 0; e < 8; ++e) {
        float hh = (float)hA[e] + (float)hB[e] + (float)bv[e];
        hh = hh > 0.f ? hh : (__expf(hh) - 1.f);
        d += hh * (float)wv[e];
      }
      d += __shfl_xor(d, 1); d += __shfl_xor(d, 2); d += __shfl_xor(d, 4);
      if ((tid & 7) == 0) {
        float b2v = b2part[0][row] + b2part[1][row] + b2part[2][row]
                  + b2part[3][row] + bb2b0;
        out[rowt + row] = d + b2v;
      }
    }
    __syncthreads();  // C: b1T/b2part/hidT free for next rt
  }
}

extern "C" void kernel_launch(void* const* d_in, const int* in_sizes, int n_in,
                              void* d_out, int out_size, void* d_ws, size_t ws_size,
                              hipStream_t stream) {
  const float* q    = (const float*)d_in[0];
  const float* s    = (const float*)d_in[1];
  const float* W1a  = (const float*)d_in[2];
  const float* b1a  = (const float*)d_in[3];
  const float* W1b  = (const float*)d_in[4];
  const float* b1b  = (const float*)d_in[5];
  const float* W2a  = (const float*)d_in[6];
  const float* b2a  = (const float*)d_in[7];
  const float* W2b  = (const float*)d_in[8];
  const float* b2b  = (const float*)d_in[9];
  const float* Wb1  = (const float*)d_in[10];
  const float* bb1  = (const float*)d_in[11];
  const float* Wb2a = (const float*)d_in[12];
  const float* bb2a = (const float*)d_in[13];
  const float* Wb2b = (const float*)d_in[14];
  const float* bb2b = (const float*)d_in[15];
  bf16_t* ws = (bf16_t*)d_ws;
  float* out = (float*)d_out;

  int N  = in_sizes[0] / 8;       // 65536 rows
  int nb = N / 256;               // 256 blocks

  cvt_frag<<<152, 256, 0, stream>>>(W1a, W2a, W1b, W2b, Wb1, Wb2a, ws);
  qmix_f2<<<nb, 512, 0, stream>>>(s, q, ws, b1a, b2a, b1b, b2b,
                                  bb1, bb2a, Wb2b, bb2b, out);
}